// Round 7
// baseline (187.983 us; speedup 1.0000x reference)
//
#include <hip/hip_runtime.h>
#include <cstddef>

typedef short short8 __attribute__((ext_vector_type(8)));
typedef unsigned short ushort8 __attribute__((ext_vector_type(8)));
typedef float f32x16 __attribute__((ext_vector_type(16)));

#define AS1(p) ((const __attribute__((address_space(1))) void*)(p))
#define AS3(p) ((__attribute__((address_space(3))) void*)(p))

__device__ __forceinline__ unsigned short f2bf(float f) {
  unsigned int u = __builtin_bit_cast(unsigned int, f);
  u += 0x7FFFu + ((u >> 16) & 1u);   // round-to-nearest-even
  return (unsigned short)(u >> 16);
}

__device__ __forceinline__ void gload_lds16(const void* g, void* l) {
  __builtin_amdgcn_global_load_lds(AS1(g), AS3(l), 16, 0, 0);
}

// ---------------------------------------------------------------------------
// fp32 -> bf16 elementwise convert
// ---------------------------------------------------------------------------
__global__ void cvt_f32_bf16(const float* __restrict__ in,
                             unsigned short* __restrict__ out, int n4) {
  int i = blockIdx.x * blockDim.x + threadIdx.x;
  if (i >= n4) return;
  float4 v = *reinterpret_cast<const float4*>(in + (size_t)i * 4);
  ushort4 o;
  o.x = f2bf(v.x); o.y = f2bf(v.y); o.z = f2bf(v.z); o.w = f2bf(v.w);
  *reinterpret_cast<ushort4*>(out + (size_t)i * 4) = o;
}

// ---------------------------------------------------------------------------
// fp32 [Kd][Nd] -> bf16 [Nd][Kd] tiled transpose+convert, block (32,8)
// ---------------------------------------------------------------------------
__global__ void transpose_cvt(const float* __restrict__ in,
                              unsigned short* __restrict__ out,
                              int Kd, int Nd) {
  __shared__ float tile[32][33];
  const int n0 = blockIdx.x * 32;
  const int k0 = blockIdx.y * 32;
  const int tx = threadIdx.x;
  const int ty = threadIdx.y;
#pragma unroll
  for (int i = 0; i < 4; ++i)
    tile[ty + i * 8][tx] = in[(size_t)(k0 + ty + i * 8) * Nd + n0 + tx];
  __syncthreads();
#pragma unroll
  for (int i = 0; i < 4; ++i)
    out[(size_t)(n0 + ty + i * 8) * Kd + k0 + tx] = f2bf(tile[tx][ty + i * 8]);
}

// ---------------------------------------------------------------------------
// GEMM: C[M][N] = A[M][K] * B'[N][K] (+bias or +C_old, optional relu+bf16 out)
// BM=128 x BN tile (BN=128 or 64), BK=64, 4 waves (2x2).
// ROUND-7 LEVER: mfma_f32_32x32x16_bf16 (half the MFMA instructions of the
// 16x16x32 version at a higher ceiling, 2382/2495 vs 2075 TF). Staging,
// LDS involution a^=((a>>7)&7)<<4 (both sides, rule #21), grid/swizzle are
// byte-identical to the round-2/6 verified structure.
// A frag: row=lane&31, k=(lane>>5)*8+e (derived from the verified 16x16x32
// pattern). C/D: col=lane&31, row=(reg&3)+8*(reg>>2)+4*(lane>>5) [m74/m101].
// ---------------------------------------------------------------------------
template <int A_F32, int BN, int RELU_BF16_OUT>
__global__ __launch_bounds__(256, 3)
void gemm_bf16(const void* __restrict__ Ap, int lda,
               const unsigned short* __restrict__ B, int ldb,
               const float* __restrict__ bias,
               void* __restrict__ C, int ldc,
               int K, int beta, int nbx) {
  constexpr int BUNITS = BN / 32;          // 4-KB stage passes for B (4 or 2)
  constexpr int MTN    = BN / 64;          // 32-wide MFMA tiles per wave (2/1)
  __shared__ char lds[16384 + BN * 128];
  char* const As = lds;
  char* const Bs = lds + 16384;

  const int tid  = threadIdx.x;
  const int lane = tid & 63;
  const int w    = tid >> 6;
  const int wm   = w >> 1;
  const int wn   = w & 1;

  // bijective XCD-chunked swizzle (grid % 8 == 0 for all our launches)
  const int cpx     = gridDim.x >> 3;
  const int logical = (blockIdx.x & 7) * cpx + (blockIdx.x >> 3);
  const int m0 = (logical / nbx) * 128;
  const int n0 = (logical % nbx) * BN;

  f32x16 acc[2][MTN];
#pragma unroll
  for (int i = 0; i < 2; ++i)
#pragma unroll
    for (int j = 0; j < MTN; ++j)
      acc[i][j] = (f32x16){0.f};

  // gload_lds staging map: linear LDS dest, pre-swizzled global source.
  int srow[4], scol[4], sbase[4];
#pragma unroll
  for (int j = 0; j < 4; ++j) {
    const int stored  = (j * 256 + tid) * 16;
    const int natural = stored ^ (((stored >> 7) & 7) << 4);
    srow[j]  = natural >> 7;          // logical tile row
    scol[j]  = (natural & 127) >> 1;  // logical k element (multiple of 8)
    sbase[j] = (j * 256 + (tid & 192)) * 16;  // wave-uniform LDS base
  }

  // A_F32 reg-staging map (fallback path): 4 groups of 8 f32 -> 8 bf16.
  size_t agofs[4];
  int ast[4];
  if (A_F32) {
#pragma unroll
    for (int p = 0; p < 4; ++p) {
      const int idx = p * 256 + tid;
      const int r   = idx >> 3;
      const int kbe = (idx & 7) * 8;
      agofs[p] = (size_t)(m0 + r) * lda + kbe;
      const int nat = r * 128 + kbe * 2;
      ast[p] = nat ^ (((nat >> 7) & 7) << 4);
    }
  }

  // ds_read swizzled offsets: per kk (K=16), A 2 frags, B MTN frags.
  // A row = wm*64 + s*32 + (lane&31); kbyte = kk*32 + (lane>>5)*16.
  int ard[4][2], brd[4][MTN];
#pragma unroll
  for (int kk = 0; kk < 4; ++kk) {
    const int kb = kk * 32 + (lane >> 5) * 16;
#pragma unroll
    for (int s = 0; s < 2; ++s) {
      const int nat = (wm * 64 + s * 32 + (lane & 31)) * 128 + kb;
      ard[kk][s] = nat ^ (((nat >> 7) & 7) << 4);
    }
#pragma unroll
    for (int t = 0; t < MTN; ++t) {
      const int nat = (wn * (BN / 2) + t * 32 + (lane & 31)) * 128 + kb;
      brd[kk][t] = nat ^ (((nat >> 7) & 7) << 4);
    }
  }

  const int nsteps = K >> 6;
  for (int ks = 0; ks < nsteps; ++ks) {
    const int k0 = ks << 6;
    if (A_F32) {
      const float* Af = (const float*)Ap;
#pragma unroll
      for (int p = 0; p < 4; ++p) {
        const float* s = Af + agofs[p] + k0;
        float4 x0 = *reinterpret_cast<const float4*>(s);
        float4 x1 = *reinterpret_cast<const float4*>(s + 4);
        ushort8 v;
        v[0] = f2bf(x0.x); v[1] = f2bf(x0.y); v[2] = f2bf(x0.z); v[3] = f2bf(x0.w);
        v[4] = f2bf(x1.x); v[5] = f2bf(x1.y); v[6] = f2bf(x1.z); v[7] = f2bf(x1.w);
        *reinterpret_cast<ushort8*>(As + ast[p]) = v;
      }
    } else {
      const unsigned short* Ab = (const unsigned short*)Ap;
#pragma unroll
      for (int j = 0; j < 4; ++j)
        gload_lds16(Ab + (size_t)(m0 + srow[j]) * lda + (k0 + scol[j]),
                    As + sbase[j]);
    }
#pragma unroll
    for (int j = 0; j < BUNITS; ++j)
      gload_lds16(B + (size_t)(n0 + srow[j]) * ldb + (k0 + scol[j]),
                  Bs + sbase[j]);
    __syncthreads();   // drains vmcnt (gload_lds) + lgkmcnt (ds_write)

#pragma unroll
    for (int kk = 0; kk < 4; ++kk) {
      short8 af[2], bfv[MTN];
#pragma unroll
      for (int s = 0; s < 2; ++s)
        af[s] = *reinterpret_cast<const short8*>(As + ard[kk][s]);
#pragma unroll
      for (int t = 0; t < MTN; ++t)
        bfv[t] = *reinterpret_cast<const short8*>(Bs + brd[kk][t]);
#pragma unroll
      for (int s = 0; s < 2; ++s)
#pragma unroll
        for (int t = 0; t < MTN; ++t)
          acc[s][t] = __builtin_amdgcn_mfma_f32_32x32x16_bf16(
              af[s], bfv[t], acc[s][t], 0, 0, 0);
    }
    __syncthreads();   // all reads done before next stage overwrites
  }

  // Epilogue: 32x32 C/D map col=lane&31, row=(reg&3)+8*(reg>>2)+4*(lane>>5)
  const int colb = n0 + wn * (BN / 2) + (lane & 31);
  const int rowb = m0 + wm * 64 + 4 * (lane >> 5);
#pragma unroll
  for (int t = 0; t < MTN; ++t) {
    const int c = colb + t * 32;
    const float bv = beta ? 0.f : bias[c];
#pragma unroll
    for (int s = 0; s < 2; ++s) {
#pragma unroll
      for (int r = 0; r < 16; ++r) {
        const int row = rowb + s * 32 + (r & 3) + 8 * (r >> 2);
        const size_t idx = (size_t)row * ldc + c;
        float v = acc[s][t][r] + bv;
        if (RELU_BF16_OUT) {
          v = v > 0.f ? v : 0.f;
          ((unsigned short*)C)[idx] = f2bf(v);
        } else {
          if (beta) v += ((float*)C)[idx];
          ((float*)C)[idx] = v;
        }
      }
    }
  }
}

// ---------------------------------------------------------------------------
extern "C" void kernel_launch(void* const* d_in, const int* in_sizes, int n_in,
                              void* d_out, int out_size, void* d_ws, size_t ws_size,
                              hipStream_t stream) {
  const float* X  = (const float*)d_in[0];  // [8192][1024]
  const float* W1 = (const float*)d_in[1];  // [1024][4096]
  const float* b1 = (const float*)d_in[2];  // [4096]
  const float* W2 = (const float*)d_in[3];  // [4096][1024]
  const float* b2 = (const float*)d_in[4];  // [1024]
  float* out = (float*)d_out;               // [8192][1024] f32

  const int M = 8192, H = 1024, I = 4096;
  const size_t MB = 1024 * 1024;

  char* ws = (char*)d_ws;
  unsigned short* W1t = (unsigned short*)ws;            // [I][H] bf16, 8 MB
  unsigned short* W2t = (unsigned short*)(ws + 8 * MB); // [H][I] bf16, 8 MB

  transpose_cvt<<<dim3(I / 32, H / 32), dim3(32, 8), 0, stream>>>(W1, W1t, H, I);
  transpose_cvt<<<dim3(H / 32, I / 32), dim3(32, 8), 0, stream>>>(W2, W2t, I, H);

  if (ws_size >= 80 * MB) {
    // Fast path. Xbf parked in d_out tail (fully consumed by L1 before the
    // single L2 dispatch writes d_out; stream-serialized).
    unsigned short* Xbf = (unsigned short*)((char*)d_out + 16 * MB);
    unsigned short* Hbf = (unsigned short*)(ws + 16 * MB);   // [M][I] bf16
    int n4 = (M * H) / 4;
    cvt_f32_bf16<<<(n4 + 255) / 256, 256, 0, stream>>>(X, Xbf, n4);
    // L1: Hbf = relu(X*W1+b1). 128x128 tiles, grid 32*64=2048.
    gemm_bf16<0, 128, 1><<<2048, 256, 0, stream>>>(
        Xbf, H, W1t, H, b1, Hbf, I, H, 0, I / 128);
    // L2: out = Hbf*W2+b2. 128x64 tiles, grid 16*64=1024.
    gemm_bf16<0, 64, 0><<<1024, 256, 0, stream>>>(
        Hbf, I, W2t, I, b2, out, H, I, 0, H / 64);
    return;
  }

  // Fallback: adaptive chunked path (same kernels, I-chunked with RMW).
  int Ic, useXbf;
  unsigned short* Xbf = nullptr;
  unsigned short* Hc;
  if (ws_size >= 64 * MB) {
    Ic = 2048; useXbf = 1;
    Xbf = (unsigned short*)(ws + 16 * MB);
    Hc  = (unsigned short*)(ws + 32 * MB);
  } else if (ws_size >= 48 * MB) {
    Ic = 1024; useXbf = 1;
    Xbf = (unsigned short*)(ws + 16 * MB);
    Hc  = (unsigned short*)(ws + 32 * MB);
  } else if (ws_size >= 32 * MB) {
    Ic = 1024; useXbf = 0;
    Hc  = (unsigned short*)(ws + 16 * MB);
  } else if (ws_size >= 24 * MB) {
    Ic = 512;  useXbf = 0;
    Hc  = (unsigned short*)(ws + 16 * MB);
  } else if (ws_size >= 20 * MB) {
    Ic = 256;  useXbf = 0;
    Hc  = (unsigned short*)(ws + 16 * MB);
  } else {
    Ic = 128;  useXbf = 0;
    Hc  = (unsigned short*)(ws + 16 * MB);
  }

  if (useXbf) {
    int n4 = (M * H) / 4;
    cvt_f32_bf16<<<(n4 + 255) / 256, 256, 0, stream>>>(X, Xbf, n4);
  }

  const int nch = I / Ic;
  for (int c = 0; c < nch; ++c) {
    const int i0 = c * Ic;
    const int nbx1 = Ic / 128;
    if (useXbf)
      gemm_bf16<0, 128, 1><<<nbx1 * (M / 128), 256, 0, stream>>>(
          Xbf, H, W1t + (size_t)i0 * H, H, b1 + i0, Hc, Ic, H, 0, nbx1);
    else
      gemm_bf16<1, 128, 1><<<nbx1 * (M / 128), 256, 0, stream>>>(
          X, H, W1t + (size_t)i0 * H, H, b1 + i0, Hc, Ic, H, 0, nbx1);
    gemm_bf16<0, 64, 0><<<(H / 64) * (M / 128), 256, 0, stream>>>(
        Hc, Ic, W2t + i0, I, b2, out, H, Ic, c > 0, H / 64);
  }
}

// Round 9
// 161.735 us; speedup vs baseline: 1.1623x; 1.1623x over previous
//
#include <hip/hip_runtime.h>
#include <cstddef>

typedef short short8 __attribute__((ext_vector_type(8)));
typedef unsigned short ushort8 __attribute__((ext_vector_type(8)));
typedef float f32x4 __attribute__((ext_vector_type(4)));

#define AS1(p) ((const __attribute__((address_space(1))) void*)(p))
#define AS3(p) ((__attribute__((address_space(3))) void*)(p))

__device__ __forceinline__ unsigned short f2bf(float f) {
  unsigned int u = __builtin_bit_cast(unsigned int, f);
  u += 0x7FFFu + ((u >> 16) & 1u);   // round-to-nearest-even
  return (unsigned short)(u >> 16);
}

__device__ __forceinline__ void gload_lds16(const void* g, void* l) {
  __builtin_amdgcn_global_load_lds(AS1(g), AS3(l), 16, 0, 0);
}

// ---------------------------------------------------------------------------
// Fused prep (ONE dispatch replaces 3): W1 transpose+cvt, W2 transpose+cvt,
// X f32->bf16.
// blocks [0,4096):      W1 [1024][4096] -> W1t [4096][1024]
// blocks [4096,8192):   W2 [4096][1024] -> W2t [1024][4096]
// blocks [8192,16384):  cvt X: 8192 blocks x 256 thr x 1 float4 = 2^21 float4
//                       = 8,388,608 floats (FULL X — round-8 bug was 1/4).
// ---------------------------------------------------------------------------
__global__ __launch_bounds__(256)
void prep_fused(const float* __restrict__ X,
                const float* __restrict__ W1,
                const float* __restrict__ W2,
                unsigned short* __restrict__ Xbf,
                unsigned short* __restrict__ W1t,
                unsigned short* __restrict__ W2t) {
  const int b   = blockIdx.x;
  const int tid = threadIdx.x;

  if (b >= 8192) {   // ---- X cvt: float4 in, 4x bf16 out ----
    const size_t i = (size_t)(b - 8192) * 256 + tid;   // 0 .. 2^21-1
    float4 v = *reinterpret_cast<const float4*>(X + i * 4);
    ushort4 o;
    o.x = f2bf(v.x); o.y = f2bf(v.y); o.z = f2bf(v.z); o.w = f2bf(v.w);
    *reinterpret_cast<ushort4*>(Xbf + i * 4) = o;
    return;
  }

  // ---- 32x32 tiled transpose+convert ----
  __shared__ float tile[32][33];
  const float* in;
  unsigned short* out;
  int Kd, Nd, n0, k0;
  if (b < 4096) {              // W1: Kd=1024 (H), Nd=4096 (I)
    in = W1; out = W1t; Kd = 1024; Nd = 4096;
    n0 = (b & 127) * 32;       // 128 n-tiles
    k0 = (b >> 7) * 32;        // 32 k-tiles
  } else {                     // W2: Kd=4096 (I), Nd=1024 (H)
    const int b2 = b - 4096;
    in = W2; out = W2t; Kd = 4096; Nd = 1024;
    n0 = (b2 & 31) * 32;       // 32 n-tiles
    k0 = (b2 >> 5) * 32;       // 128 k-tiles
  }
  const int tx = tid & 31;
  const int ty = tid >> 5;     // 0..7
#pragma unroll
  for (int i = 0; i < 4; ++i)
    tile[ty + i * 8][tx] = in[(size_t)(k0 + ty + i * 8) * Nd + n0 + tx];
  __syncthreads();
#pragma unroll
  for (int i = 0; i < 4; ++i)
    out[(size_t)(n0 + ty + i * 8) * Kd + k0 + tx] = f2bf(tile[tx][ty + i * 8]);
}

// ---------------------------------------------------------------------------
// Standalone prep kernels (fallback path only).
// ---------------------------------------------------------------------------
__global__ void cvt_f32_bf16(const float* __restrict__ in,
                             unsigned short* __restrict__ out, int n4) {
  int i = blockIdx.x * blockDim.x + threadIdx.x;
  if (i >= n4) return;
  float4 v = *reinterpret_cast<const float4*>(in + (size_t)i * 4);
  ushort4 o;
  o.x = f2bf(v.x); o.y = f2bf(v.y); o.z = f2bf(v.z); o.w = f2bf(v.w);
  *reinterpret_cast<ushort4*>(out + (size_t)i * 4) = o;
}

__global__ void transpose_cvt(const float* __restrict__ in,
                              unsigned short* __restrict__ out,
                              int Kd, int Nd) {
  __shared__ float tile[32][33];
  const int n0 = blockIdx.x * 32;
  const int k0 = blockIdx.y * 32;
  const int tx = threadIdx.x;
  const int ty = threadIdx.y;
#pragma unroll
  for (int i = 0; i < 4; ++i)
    tile[ty + i * 8][tx] = in[(size_t)(k0 + ty + i * 8) * Nd + n0 + tx];
  __syncthreads();
#pragma unroll
  for (int i = 0; i < 4; ++i)
    out[(size_t)(n0 + ty + i * 8) * Kd + k0 + tx] = f2bf(tile[tx][ty + i * 8]);
}

// ---------------------------------------------------------------------------
// 8-phase 256-row GEMM — VERBATIM the round-3 kernel (passed, absmax 0.0156).
// ---------------------------------------------------------------------------
#define PH(ABUF, BBUF, H, KK, STAGE, WAITC)                                    \
  {                                                                            \
    if ((H) == 0) {                                                            \
      _Pragma("unroll")                                                        \
      for (int ni = 0; ni < NB; ++ni)                                          \
        bfr[ni] = *reinterpret_cast<const short8*>((BBUF) + bread[ni][KK]);    \
    }                                                                          \
    short8 afr[4];                                                             \
    _Pragma("unroll")                                                          \
    for (int m2 = 0; m2 < 4; ++m2)                                             \
      afr[m2] = *reinterpret_cast<const short8*>((ABUF) + aread[(H)*4+m2][KK]);\
    STAGE;                                                                     \
    __builtin_amdgcn_s_barrier();                                              \
    asm volatile("s_waitcnt lgkmcnt(0)" ::: "memory");                         \
    __builtin_amdgcn_sched_barrier(0);                                         \
    __builtin_amdgcn_s_setprio(1);                                             \
    _Pragma("unroll")                                                          \
    for (int m2 = 0; m2 < 4; ++m2) {                                           \
      _Pragma("unroll")                                                        \
      for (int ni = 0; ni < NB; ++ni)                                          \
        acc[(H)*4+m2][ni] = __builtin_amdgcn_mfma_f32_16x16x32_bf16(           \
            afr[m2], bfr[ni], acc[(H)*4+m2][ni], 0, 0, 0);                     \
    }                                                                          \
    __builtin_amdgcn_s_setprio(0);                                             \
    WAITC;                                                                     \
    __builtin_amdgcn_s_barrier();                                              \
  }

template <int BN, int RELU_BF16_OUT>
__global__ __launch_bounds__(512, 2)
void gemm8p(const unsigned short* __restrict__ A, int lda,
            const unsigned short* __restrict__ Bp, int ldb,
            const float* __restrict__ bias,
            void* __restrict__ C, int ldc, int K, int nbx) {
  constexpr int PWN     = BN / 4;        // per-wave N (64 or 32)
  constexpr int NB      = PWN / 16;      // B frags per wave (4 or 2)
  constexpr int LOADS_B = BN / 128;      // gload_lds per B-half (2 or 1)
  constexpr int BHROWS  = BN / 2;        // rows per B-half
  constexpr int BHSZ    = BHROWS * 128;  // bytes per B-half
  extern __shared__ char lds[];
  char* const A0b = lds;
  char* const A1b = lds + 32768;
  char* const B0b = lds + 65536;
  char* const B1b = lds + 65536 + 2 * BHSZ;

  const int tid  = threadIdx.x;
  const int lane = tid & 63;
  const int wid  = tid >> 6;
  const int wm   = wid >> 2;
  const int wn   = wid & 3;

  const int cpx     = gridDim.x >> 3;
  const int logical = (blockIdx.x & 7) * cpx + (blockIdx.x >> 3);
  const int bx = logical % nbx;
  const int by = logical / nbx;
  const int m0 = by * 256;
  const int n0 = bx * BN;

  f32x4 acc[8][NB];
#pragma unroll
  for (int i = 0; i < 8; ++i)
#pragma unroll
    for (int j = 0; j < NB; ++j)
      acc[i][j] = (f32x4){0.f, 0.f, 0.f, 0.f};

  size_t aofs0, aofs1, bofs0, bofs1 = 0;
  {
    int sr = tid * 16, nat = sr ^ (((sr >> 7) & 7) << 4);
    aofs0 = (size_t)(m0 + (nat >> 7)) * lda + ((nat & 127) >> 1);
    bofs0 = (size_t)(n0 + (nat >> 7)) * ldb + ((nat & 127) >> 1);
    sr = (512 + tid) * 16; nat = sr ^ (((sr >> 7) & 7) << 4);
    aofs1 = (size_t)(m0 + (nat >> 7)) * lda + ((nat & 127) >> 1);
    if (LOADS_B == 2)
      bofs1 = (size_t)(n0 + (nat >> 7)) * ldb + ((nat & 127) >> 1);
  }
  const int dst0 = (tid & 448) * 16;
  const int dst1 = dst0 + 8192;

  auto stA = [&](char* ab, int half, int kel) {
    gload_lds16(A + aofs0 + (size_t)half * 128 * lda + kel, ab + half * 16384 + dst0);
    gload_lds16(A + aofs1 + (size_t)half * 128 * lda + kel, ab + half * 16384 + dst1);
  };
  auto stB = [&](char* bb, int half, int kel) {
    gload_lds16(Bp + bofs0 + (size_t)half * BHROWS * ldb + kel, bb + half * BHSZ + dst0);
    if constexpr (LOADS_B == 2)
      gload_lds16(Bp + bofs1 + (size_t)half * BHROWS * ldb + kel, bb + half * BHSZ + dst1);
  };
  auto waitLB = [&]() {
    if constexpr (LOADS_B == 2) asm volatile("s_waitcnt vmcnt(2)" ::: "memory");
    else                        asm volatile("s_waitcnt vmcnt(1)" ::: "memory");
  };

  int aread[8][2], bread[NB][2];
#pragma unroll
  for (int mi = 0; mi < 8; ++mi)
#pragma unroll
    for (int kk = 0; kk < 2; ++kk) {
      int nat = (wm * 128 + mi * 16 + (lane & 15)) * 128 + kk * 64 + (lane >> 4) * 16;
      aread[mi][kk] = nat ^ (((nat >> 7) & 7) << 4);
    }
#pragma unroll
  for (int ni = 0; ni < NB; ++ni)
#pragma unroll
    for (int kk = 0; kk < 2; ++kk) {
      int nat = (wn * PWN + ni * 16 + (lane & 15)) * 128 + kk * 64 + (lane >> 4) * 16;
      bread[ni][kk] = nat ^ (((nat >> 7) & 7) << 4);
    }

  stB(B0b, 0, 0);
  stB(B0b, 1, 0);
  stA(A0b, 0, 0);
  stA(A0b, 1, 0);
  stB(B1b, 0, 64);
  waitLB();
  __builtin_amdgcn_s_barrier();

  const int niter = K >> 7;
  for (int it = 0; it < niter; ++it) {
    const bool last = (it == niter - 1);
    const int kb = it << 7;
    short8 bfr[NB];
    PH(A0b, B0b, 0, 0, stB(B1b, 1, kb + 64), ((void)0));
    PH(A0b, B0b, 1, 0, stA(A1b, 0, kb + 64), ((void)0));
    PH(A0b, B0b, 0, 1, stA(A1b, 1, kb + 64), ((void)0));
    PH(A0b, B0b, 1, 1, { if (!last) stB(B0b, 0, kb + 128); },
       { if (last) { asm volatile("s_waitcnt vmcnt(0)" ::: "memory"); } else waitLB(); });
    PH(A1b, B1b, 0, 0, { if (!last) stB(B0b, 1, kb + 128); }, ((void)0));
    PH(A1b, B1b, 1, 0, { if (!last) stA(A0b, 0, kb + 128); }, ((void)0));
    PH(A1b, B1b, 0, 1, { if (!last) stA(A0b, 1, kb + 128); }, ((void)0));
    PH(A1b, B1b, 1, 1, { if (!last) stB(B1b, 0, kb + 192); },
       { if (!last) waitLB(); });
  }

  const int row0 = m0 + wm * 128 + (lane >> 4) * 4;
  const int col0 = n0 + wn * PWN + (lane & 15);
#pragma unroll
  for (int ni = 0; ni < NB; ++ni) {
    const int c = col0 + ni * 16;
    const float bv = bias[c];
#pragma unroll
    for (int mi = 0; mi < 8; ++mi) {
#pragma unroll
      for (int r = 0; r < 4; ++r) {
        const size_t idx = (size_t)(row0 + mi * 16 + r) * ldc + c;
        float v = acc[mi][ni][r] + bv;
        if (RELU_BF16_OUT) {
          v = v > 0.f ? v : 0.f;
          ((unsigned short*)C)[idx] = f2bf(v);
        } else {
          ((float*)C)[idx] = v;
        }
      }
    }
  }
}

// ---------------------------------------------------------------------------
// Fallback 128^2 GEMM (round-2, verified) for small-ws configurations.
// ---------------------------------------------------------------------------
template <int A_F32, int RELU_BF16_OUT>
__global__ __launch_bounds__(256, 2)
void gemm_bf16(const void* __restrict__ Ap, int lda,
               const unsigned short* __restrict__ B, int ldb,
               const float* __restrict__ bias,
               void* __restrict__ C, int ldc,
               int K, int beta) {
  __shared__ char lds[32768];
  char* const As = lds;
  char* const Bs = lds + 16384;

  const int tid  = threadIdx.x;
  const int lane = tid & 63;
  const int w    = tid >> 6;
  const int wm   = w >> 1;
  const int wn   = w & 1;
  const int m0   = blockIdx.y * 128;
  const int n0   = blockIdx.x * 128;

  f32x4 acc[4][4];
#pragma unroll
  for (int i = 0; i < 4; ++i)
#pragma unroll
    for (int j = 0; j < 4; ++j)
      acc[i][j] = (f32x4){0.f, 0.f, 0.f, 0.f};

  int srow[4], scol[4], sbase[4];
#pragma unroll
  for (int j = 0; j < 4; ++j) {
    const int stored  = (j * 256 + tid) * 16;
    const int natural = stored ^ (((stored >> 7) & 7) << 4);
    srow[j]  = natural >> 7;
    scol[j]  = (natural & 127) >> 1;
    sbase[j] = (j * 256 + (tid & 192)) * 16;
  }

  size_t agofs[4];
  int ast[4];
  if (A_F32) {
#pragma unroll
    for (int pq = 0; pq < 4; ++pq) {
      const int idx = pq * 256 + tid;
      const int rr  = idx >> 3;
      const int kbe = (idx & 7) * 8;
      agofs[pq] = (size_t)(m0 + rr) * lda + kbe;
      const int nat = rr * 128 + kbe * 2;
      ast[pq] = nat ^ (((nat >> 7) & 7) << 4);
    }
  }

  const int nsteps = K >> 6;
  for (int ks = 0; ks < nsteps; ++ks) {
    const int k0 = ks << 6;
    if (A_F32) {
      const float* Af = (const float*)Ap;
#pragma unroll
      for (int pq = 0; pq < 4; ++pq) {
        const float* sp = Af + agofs[pq] + k0;
        float4 x0 = *reinterpret_cast<const float4*>(sp);
        float4 x1 = *reinterpret_cast<const float4*>(sp + 4);
        ushort8 v;
        v[0] = f2bf(x0.x); v[1] = f2bf(x0.y); v[2] = f2bf(x0.z); v[3] = f2bf(x0.w);
        v[4] = f2bf(x1.x); v[5] = f2bf(x1.y); v[6] = f2bf(x1.z); v[7] = f2bf(x1.w);
        *reinterpret_cast<ushort8*>(As + ast[pq]) = v;
      }
    } else {
      const unsigned short* Ab = (const unsigned short*)Ap;
#pragma unroll
      for (int j = 0; j < 4; ++j)
        gload_lds16(Ab + (size_t)(m0 + srow[j]) * lda + (k0 + scol[j]),
                    As + sbase[j]);
    }
#pragma unroll
    for (int j = 0; j < 4; ++j)
      gload_lds16(B + (size_t)(n0 + srow[j]) * ldb + (k0 + scol[j]),
                  Bs + sbase[j]);
    __syncthreads();

#pragma unroll
    for (int kk = 0; kk < 2; ++kk) {
      const int kb = kk * 64 + (lane >> 4) * 16;
      short8 af[4], bfv[4];
#pragma unroll
      for (int mi = 0; mi < 4; ++mi) {
        int nat = (wm * 64 + mi * 16 + (lane & 15)) * 128 + kb;
        int st  = nat ^ (((nat >> 7) & 7) << 4);
        af[mi] = *reinterpret_cast<const short8*>(As + st);
      }
#pragma unroll
      for (int ni = 0; ni < 4; ++ni) {
        int nat = (wn * 64 + ni * 16 + (lane & 15)) * 128 + kb;
        int st  = nat ^ (((nat >> 7) & 7) << 4);
        bfv[ni] = *reinterpret_cast<const short8*>(Bs + st);
      }
#pragma unroll
      for (int mi = 0; mi < 4; ++mi)
#pragma unroll
        for (int ni = 0; ni < 4; ++ni)
          acc[mi][ni] = __builtin_amdgcn_mfma_f32_16x16x32_bf16(
              af[mi], bfv[ni], acc[mi][ni], 0, 0, 0);
    }
    __syncthreads();
  }

  const int row0 = m0 + wm * 64 + (lane >> 4) * 4;
  const int col0 = n0 + wn * 64 + (lane & 15);
#pragma unroll
  for (int ni = 0; ni < 4; ++ni) {
    const int c = col0 + ni * 16;
    const float bv = beta ? 0.f : bias[c];
#pragma unroll
    for (int mi = 0; mi < 4; ++mi) {
#pragma unroll
      for (int rr = 0; rr < 4; ++rr) {
        const size_t idx = (size_t)(row0 + mi * 16 + rr) * ldc + c;
        float v = acc[mi][ni][rr] + bv;
        if (RELU_BF16_OUT) {
          v = v > 0.f ? v : 0.f;
          ((unsigned short*)C)[idx] = f2bf(v);
        } else {
          if (beta) v += ((float*)C)[idx];
          ((float*)C)[idx] = v;
        }
      }
    }
  }
}

// ---------------------------------------------------------------------------
extern "C" void kernel_launch(void* const* d_in, const int* in_sizes, int n_in,
                              void* d_out, int out_size, void* d_ws, size_t ws_size,
                              hipStream_t stream) {
  const float* X  = (const float*)d_in[0];  // [8192][1024]
  const float* W1 = (const float*)d_in[1];  // [1024][4096]
  const float* b1 = (const float*)d_in[2];  // [4096]
  const float* W2 = (const float*)d_in[3];  // [4096][1024]
  const float* b2 = (const float*)d_in[4];  // [1024]
  float* out = (float*)d_out;               // [8192][1024] f32

  const int M = 8192, H = 1024, I = 4096;
  const size_t MB = 1024 * 1024;

  char* ws = (char*)d_ws;
  unsigned short* W1t = (unsigned short*)ws;            // [I][H] bf16, 8 MB
  unsigned short* W2t = (unsigned short*)(ws + 8 * MB); // [H][I] bf16, 8 MB

  if (ws_size >= 80 * MB) {
    // Fast path (round-3 config + fused prep). Xbf parked in d_out tail
    // (fully consumed by L1 before the single L2 dispatch writes d_out).
    unsigned short* Xbf = (unsigned short*)((char*)d_out + 16 * MB);
    unsigned short* Hbf = (unsigned short*)(ws + 16 * MB);   // [M][I] bf16
    // ONE prep dispatch: both W transposes (8192 blocks) + full X cvt (8192).
    prep_fused<<<16384, 256, 0, stream>>>(X, W1, W2, Xbf, W1t, W2t);
    // L1: Hbf = relu(X*W1+b1). 256x256 tiles, grid 16x32=512, LDS 128 KiB.
    gemm8p<256, 1><<<512, 512, 131072, stream>>>(Xbf, H, W1t, H, b1, Hbf, I, H, I / 256);
    // L2: out = Hbf*W2+b2. 256x128 tiles, grid 8x32=256, LDS 96 KiB.
    gemm8p<128, 0><<<256, 512, 98304, stream>>>(Hbf, I, W2t, I, b2, out, H, I, H / 128);
    return;
  }

  // Fallback: adaptive chunked path (round-2 verified kernels).
  transpose_cvt<<<dim3(I / 32, H / 32), dim3(32, 8), 0, stream>>>(W1, W1t, H, I);
  transpose_cvt<<<dim3(H / 32, I / 32), dim3(32, 8), 0, stream>>>(W2, W2t, I, H);

  int Ic, useXbf;
  unsigned short* Xbf = nullptr;
  unsigned short* Hc;
  if (ws_size >= 64 * MB) {
    Ic = 2048; useXbf = 1;
    Xbf = (unsigned short*)(ws + 16 * MB);
    Hc  = (unsigned short*)(ws + 32 * MB);
  } else if (ws_size >= 48 * MB) {
    Ic = 1024; useXbf = 1;
    Xbf = (unsigned short*)(ws + 16 * MB);
    Hc  = (unsigned short*)(ws + 32 * MB);
  } else if (ws_size >= 32 * MB) {
    Ic = 1024; useXbf = 0;
    Hc  = (unsigned short*)(ws + 16 * MB);
  } else if (ws_size >= 24 * MB) {
    Ic = 512;  useXbf = 0;
    Hc  = (unsigned short*)(ws + 16 * MB);
  } else if (ws_size >= 20 * MB) {
    Ic = 256;  useXbf = 0;
    Hc  = (unsigned short*)(ws + 16 * MB);
  } else {
    Ic = 128;  useXbf = 0;
    Hc  = (unsigned short*)(ws + 16 * MB);
  }

  if (useXbf) {
    int n4 = (M * H) / 4;
    cvt_f32_bf16<<<(n4 + 255) / 256, 256, 0, stream>>>(X, Xbf, n4);
  }

  const int nch = I / Ic;
  for (int c = 0; c < nch; ++c) {
    const int i0 = c * Ic;
    if (useXbf)
      gemm_bf16<0, 1><<<dim3(Ic / 128, M / 128), 256, 0, stream>>>(
          Xbf, H, W1t + (size_t)i0 * H, H, b1 + i0, Hc, Ic, H, 0);
    else
      gemm_bf16<1, 1><<<dim3(Ic / 128, M / 128), 256, 0, stream>>>(
          X, H, W1t + (size_t)i0 * H, H, b1 + i0, Hc, Ic, H, 0);
    gemm_bf16<0, 0><<<dim3(H / 128, M / 128), 256, 0, stream>>>(
        Hc, Ic, W2t + i0, I, b2, out, H, Ic, c > 0);
  }
}